// Round 14
// baseline (57.472 us; speedup 1.0000x reference)
//
#include <hip/hip_runtime.h>
#include <hip/hip_bf16.h>

// Shapes fixed by the reference: B=8, C=32, H=64, W=512, NCHW.
#define CH   32
#define WD   512
#define NH   64
#define CHST (NH * WD)      // channel stride in floats
#define BST  (CH * CHST)    // batch stride in floats
#define NST  36             // N LDS row stride in f32 (144B: 16B-aligned)

typedef short bf16x8 __attribute__((ext_vector_type(8)));
typedef float f32x16 __attribute__((ext_vector_type(16)));
typedef float f32x8  __attribute__((ext_vector_type(8)));

__device__ __forceinline__ unsigned short f2bf(float f) {
  union { __hip_bfloat16 h; unsigned short u; } cv;
  cv.h = __float2bfloat16(f);
  return cv.u;
}
__device__ __forceinline__ float bf2f(unsigned short u) {
  return __uint_as_float(((unsigned int)u) << 16);
}
__device__ __forceinline__ unsigned int pk2(float lo_, float hi_) {
  return ((unsigned int)f2bf(hi_) << 16) | (unsigned int)f2bf(lo_);
}
// v_permlane32_swap_b32 a,b — half-swap. ONLY safe when a,b are distinct SSA
// values (regalloc may coalesce identical values into one VGPR — R7's bug).
__device__ __forceinline__ void swap32(unsigned int& a, unsigned int& b) {
  asm volatile("v_permlane32_swap_b32 %0, %1" : "+v"(a), "+v"(b));
}
union W4 { unsigned int u[4]; bf16x8 v; };

// D-layout f32x16 -> two B-fragments (bf16) of the same matrix (verified R3-R13).
__device__ __forceinline__ void d2frag(const f32x16& d, W4& f0, W4& f1) {
  f0.u[0] = pk2(d[0], d[1]);   f0.u[1] = pk2(d[2],  d[3]);
  f0.u[2] = pk2(d[4], d[5]);   f0.u[3] = pk2(d[6],  d[7]);
  swap32(f0.u[0], f0.u[2]);    swap32(f0.u[1], f0.u[3]);
  f1.u[0] = pk2(d[8], d[9]);   f1.u[1] = pk2(d[10], d[11]);
  f1.u[2] = pk2(d[12], d[13]); f1.u[3] = pk2(d[14], d[15]);
  swap32(f1.u[0], f1.u[2]);    swap32(f1.u[1], f1.u[3]);
}
// cross-half sum via shuffle — immune to the asm coalescing hazard (R8-verified).
__device__ __forceinline__ float halfsum(float v) {
  return v + __shfl_xor(v, 32, 64);
}

// Producer/consumer split. Grid 1024, 512 thr each; ALL blocks co-resident
// (4/CU: LDS 4x39KB=156<160KB, 32 waves, VGPR<=128) -> spin cannot deadlock.
//  blocks 0..511   = producer for head bid:   k/v stream -> N -> chain -> export
//                    G (bf16 A-frags, 2KB) + g (128B) -> RELEASE flag. Never waits.
//  blocks 512..1023= consumer for head bid-512: issue q loads -> spin flag (t0,
//                    s_sleep) -> relaxed-AGENT load G/g (R12-proven coherence
//                    pattern) -> out = G^T q + g. No LDS, no weights.
// Each k/v/q byte read once (R9 lesson); one-directional 2KB-flag sync (R12
// lesson); concurrency from independent blocks (R8/R11 lesson).
//   N = K*V^T; M = Wk*N*Wv^T + (Wk sK) bv^T + bk (Wv sV + 512 bv)^T
//   G = Wq^T*M (+I residual), g = bq*M;  out = G^T q + g.
// MFMA 32x32x16 layouts (verified): A: a[s][j]=A[lo][16s+8hi+j];
// B: b[s][j]=B[16s+8hi+j][lo]; D: d[r]=D[(r&3)+8(r>>2)+4hi][lo].
__global__ __launch_bounds__(512, 4)
void fused_mha_pc(const float* __restrict__ qg, const float* __restrict__ kg,
                  const float* __restrict__ vg,
                  const float* __restrict__ wqg, const float* __restrict__ bqg,
                  const float* __restrict__ wkg, const float* __restrict__ bkg,
                  const float* __restrict__ wvg, const float* __restrict__ bvg,
                  float* __restrict__ outg,
                  unsigned int* __restrict__ GWu, float* __restrict__ gwf,
                  unsigned int* __restrict__ flagws)
{
  __shared__ float np[8][CH][NST];   // producer only
  __shared__ float sp[8][2][CH];

  const int t = threadIdx.x, lane = t & 63, wid = t >> 6;   // wid 0..7
  const int lo = lane & 31, hi = lane >> 5;
  const int bid = blockIdx.x;
  const bool producer = bid < 512;
  const int bh = producer ? bid : bid - 512;
  const size_t base = (size_t)(bh >> 6) * BST + (size_t)(bh & 63) * WD;

  int rowr[16];
  #pragma unroll
  for (int r = 0; r < 16; ++r) rowr[r] = (r & 3) + 8 * (r >> 2) + 4 * hi;

  if (producer) {
    // ---- k/v loads (the only global reads this block does) ------------------------
    const float* krow = kg + base + (size_t)lo * CHST + 64 * wid + 8 * hi;
    const float* vrow = vg + base + (size_t)lo * CHST + 64 * wid + 8 * hi;
    f32x8 kf[4], vf[4];
    #pragma unroll
    for (int kk = 0; kk < 4; ++kk) {
      kf[kk] = *(const f32x8*)(krow + 16 * kk);
      vf[kk] = *(const f32x8*)(vrow + 16 * kk);
    }
    // Weights/biases
    bf16x8 wkA[2], wvA[2], wqA[2];
    {
      const float* wk_r = wkg + lo * CH + 8 * hi;
      const float* wv_r = wvg + lo * CH + 8 * hi;
      #pragma unroll
      for (int s = 0; s < 2; ++s)
        #pragma unroll
        for (int j = 0; j < 8; ++j) {
          wkA[s][j] = (short)f2bf(wk_r[16 * s + j]);
          wvA[s][j] = (short)f2bf(wv_r[16 * s + j]);
          wqA[s][j] = (short)f2bf(wqg[(16 * s + 8 * hi + j) * CH + lo]);
        }
    }
    float bkr[16], bqr[16];
    #pragma unroll
    for (int r = 0; r < 16; ++r) { bkr[r] = bkg[rowr[r]]; bqr[r] = bqg[rowr[r]]; }
    const float bvlo = bvg[lo];

    // ---- Phase 1: N partial + sK/sV partial ---------------------------------------
    f32x16 nacc;
    #pragma unroll
    for (int r = 0; r < 16; ++r) nacc[r] = 0.f;
    float psK = 0.f, psV = 0.f;
    #pragma unroll
    for (int kk = 0; kk < 4; ++kk) {
      W4 kb, vb;
      #pragma unroll
      for (int i = 0; i < 4; ++i) {
        kb.u[i] = pk2(kf[kk][2 * i], kf[kk][2 * i + 1]);
        vb.u[i] = pk2(vf[kk][2 * i], vf[kk][2 * i + 1]);
      }
      nacc = __builtin_amdgcn_mfma_f32_32x32x16_bf16(kb.v, vb.v, nacc, 0, 0, 0);
      #pragma unroll
      for (int j = 0; j < 8; ++j) { psK += kf[kk][j]; psV += vf[kk][j]; }
    }
    #pragma unroll
    for (int r = 0; r < 16; ++r) np[wid][rowr[r]][lo] = nacc[r];
    {
      const float sk = halfsum(psK), sv = halfsum(psV);
      if (hi == 0) { sp[wid][0][lo] = sk; sp[wid][1][lo] = sv; }
    }
    __syncthreads();

    // ---- Reduce 8 partials ---------------------------------------------------------
    {
      #pragma unroll
      for (int p = 0; p < 2; ++p) {
        const int e = t + 512 * p, o = e >> 5, c = e & 31;
        float s = 0.f;
        #pragma unroll
        for (int w = 0; w < 8; ++w) s += np[w][o][c];
        np[0][o][c] = s;
      }
      if (t < 64) {
        const int j = t >> 5, oo = t & 31;
        float s2 = 0.f;
        #pragma unroll
        for (int w = 0; w < 8; ++w) s2 += sp[w][j][oo];
        sp[0][j][oo] = s2;
      }
    }
    __syncthreads();

    // ---- Chain (verified R5-R13) ----------------------------------------------------
    W4 NAh[2], NAl[2];
    #pragma unroll
    for (int s = 0; s < 2; ++s) {
      f32x8 nf = *(const f32x8*)&np[0][lo][16 * s + 8 * hi];
      #pragma unroll
      for (int i = 0; i < 4; ++i) {
        const float x = nf[2 * i], y = nf[2 * i + 1];
        const unsigned short hx = f2bf(x), hy = f2bf(y);
        NAh[s].u[i] = ((unsigned int)hy << 16) | hx;
        NAl[s].u[i] = pk2(x - bf2f(hx), y - bf2f(hy));
      }
    }
    f32x16 pacc;
    #pragma unroll
    for (int r = 0; r < 16; ++r) pacc[r] = 0.f;
    pacc = __builtin_amdgcn_mfma_f32_32x32x16_bf16(NAh[0].v, wvA[0], pacc, 0, 0, 0);
    pacc = __builtin_amdgcn_mfma_f32_32x32x16_bf16(NAh[1].v, wvA[1], pacc, 0, 0, 0);
    pacc = __builtin_amdgcn_mfma_f32_32x32x16_bf16(NAl[0].v, wvA[0], pacc, 0, 0, 0);
    pacc = __builtin_amdgcn_mfma_f32_32x32x16_bf16(NAl[1].v, wvA[1], pacc, 0, 0, 0);
    f32x16 pp;
    #pragma unroll
    for (int r = 0; r < 16; ++r) pp[r] = pacc[r] + sp[0][0][rowr[r]] * bvlo;
    float uprt = 0.f;
    #pragma unroll
    for (int s = 0; s < 2; ++s)
      #pragma unroll
      for (int j = 0; j < 8; ++j)
        uprt += bf2f((unsigned short)wvA[s][j]) * sp[0][1][16 * s + 8 * hi + j];
    const float uful = halfsum(uprt) + 512.f * bvlo;
    f32x16 pres;
    #pragma unroll
    for (int r = 0; r < 16; ++r) pres[r] = pp[r] - bf2f(f2bf(pp[r]));
    W4 pb0h, pb1h, pb0l, pb1l;
    d2frag(pp, pb0h, pb1h);
    d2frag(pres, pb0l, pb1l);
    f32x16 mac;
    #pragma unroll
    for (int r = 0; r < 16; ++r) mac[r] = bkr[r] * uful;
    mac = __builtin_amdgcn_mfma_f32_32x32x16_bf16(wkA[0], pb0h.v, mac, 0, 0, 0);
    mac = __builtin_amdgcn_mfma_f32_32x32x16_bf16(wkA[1], pb1h.v, mac, 0, 0, 0);
    mac = __builtin_amdgcn_mfma_f32_32x32x16_bf16(wkA[0], pb0l.v, mac, 0, 0, 0);
    mac = __builtin_amdgcn_mfma_f32_32x32x16_bf16(wkA[1], pb1l.v, mac, 0, 0, 0);
    W4 mb0, mb1;
    d2frag(mac, mb0, mb1);
    f32x16 gacc;
    #pragma unroll
    for (int r = 0; r < 16; ++r) gacc[r] = 0.f;
    gacc = __builtin_amdgcn_mfma_f32_32x32x16_bf16(wqA[0], mb0.v, gacc, 0, 0, 0);
    gacc = __builtin_amdgcn_mfma_f32_32x32x16_bf16(wqA[1], mb1.v, gacc, 0, 0, 0);
    #pragma unroll
    for (int r = 0; r < 16; ++r)
      if (rowr[r] == lo) gacc[r] += 1.f;          // residual: +I on G's diagonal
    float part = 0.f;
    #pragma unroll
    for (int r = 0; r < 16; ++r) part = fmaf(bqr[r], mac[r], part);
    const float gv = halfsum(part);                // g[lo]
    W4 ga0, ga1;
    d2frag(gacc, ga0, ga1);

    // ---- Export G fragments + g (wave 0), then RELEASE flag ------------------------
    if (wid == 0) {
      const int li = hi * 32 + lo;
      unsigned int* gp = GWu + (size_t)bh * 512 + li * 4;
      #pragma unroll
      for (int i = 0; i < 4; ++i) {
        __hip_atomic_store(gp + i, ga0.u[i], __ATOMIC_RELAXED,
                           __HIP_MEMORY_SCOPE_AGENT);
        __hip_atomic_store(gp + 256 + i, ga1.u[i], __ATOMIC_RELAXED,
                           __HIP_MEMORY_SCOPE_AGENT);
      }
      if (hi == 0)
        __hip_atomic_store((unsigned int*)&gwf[bh * 32 + lo], __float_as_uint(gv),
                           __ATOMIC_RELAXED, __HIP_MEMORY_SCOPE_AGENT);
      if (t == 0)
        __hip_atomic_store(&flagws[bh], 1u, __ATOMIC_RELEASE,
                           __HIP_MEMORY_SCOPE_AGENT);
    }
  } else {
    // ================= CONSUMER: out = G^T q + g over all 512 px ===================
    // Issue q loads first — latency hides under the flag spin.
    float qpf[32];
    #pragma unroll
    for (int it = 0; it < 2; ++it)
      #pragma unroll
      for (int s = 0; s < 2; ++s)
        #pragma unroll
        for (int j = 0; j < 8; ++j)
          qpf[16 * it + 8 * s + j] =
              qg[base + (size_t)(16 * s + 8 * hi + j) * CHST + 64 * wid + 32 * it + lo];

    if (t == 0) {
      while (__hip_atomic_load(&flagws[bh], __ATOMIC_ACQUIRE,
                               __HIP_MEMORY_SCOPE_AGENT) == 0u)
        __builtin_amdgcn_s_sleep(8);
    }
    __syncthreads();

    // G fragments + g via relaxed AGENT loads (coherent past XCD L2; R12 pattern)
    const int li = hi * 32 + lo;
    W4 ga0, ga1;
    const unsigned int* gp = GWu + (size_t)bh * 512 + li * 4;
    #pragma unroll
    for (int i = 0; i < 4; ++i) {
      ga0.u[i] = __hip_atomic_load(gp + i, __ATOMIC_RELAXED,
                                   __HIP_MEMORY_SCOPE_AGENT);
      ga1.u[i] = __hip_atomic_load(gp + 256 + i, __ATOMIC_RELAXED,
                                   __HIP_MEMORY_SCOPE_AGENT);
    }
    float gsh[16];
    #pragma unroll
    for (int r = 0; r < 16; ++r)
      gsh[r] = __uint_as_float(
          __hip_atomic_load((const unsigned int*)&gwf[bh * 32 + rowr[r]],
                            __ATOMIC_RELAXED, __HIP_MEMORY_SCOPE_AGENT));

    #pragma unroll
    for (int it = 0; it < 2; ++it) {
      const int x0 = 64 * wid + 32 * it;
      bf16x8 qb[2];
      #pragma unroll
      for (int s = 0; s < 2; ++s)
        #pragma unroll
        for (int j = 0; j < 8; ++j)
          qb[s][j] = (short)f2bf(qpf[16 * it + 8 * s + j]);
      f32x16 acc;
      #pragma unroll
      for (int r = 0; r < 16; ++r) acc[r] = gsh[r];
      acc = __builtin_amdgcn_mfma_f32_32x32x16_bf16(ga0.v, qb[0], acc, 0, 0, 0);
      acc = __builtin_amdgcn_mfma_f32_32x32x16_bf16(ga1.v, qb[1], acc, 0, 0, 0);
      #pragma unroll
      for (int r = 0; r < 16; ++r)
        outg[base + (size_t)rowr[r] * CHST + x0 + lo] = acc[r];
    }
  }
}

extern "C" void kernel_launch(void* const* d_in, const int* in_sizes, int n_in,
                              void* d_out, int out_size, void* d_ws, size_t ws_size,
                              hipStream_t stream) {
  const float* q  = (const float*)d_in[0];
  const float* k  = (const float*)d_in[1];
  const float* v  = (const float*)d_in[2];
  const float* wq = (const float*)d_in[3];
  const float* bq = (const float*)d_in[4];
  const float* wk = (const float*)d_in[5];
  const float* bk = (const float*)d_in[6];
  const float* wv = (const float*)d_in[7];
  const float* bv = (const float*)d_in[8];
  float* out = (float*)d_out;

  // Workspace: GWu u32[512*512] (1MB) | gwf f32[512*32] (64KB) | flags u32[512]
  unsigned int* GWu = (unsigned int*)d_ws;
  float* gwf = (float*)(GWu + 512 * 512);
  unsigned int* flagws = (unsigned int*)(gwf + 512 * 32);

  (void)in_sizes; (void)n_in; (void)out_size; (void)ws_size;

  hipMemsetAsync(flagws, 0, 512 * sizeof(unsigned int), stream);  // flags only
  fused_mha_pc<<<dim3(1024), dim3(512), 0, stream>>>(q, k, v, wq, bq, wk, bk, wv, bv,
                                                     out, GWu, gwf, flagws);
}

// Round 15
// 28.851 us; speedup vs baseline: 1.9920x; 1.9920x over previous
//
#include <hip/hip_runtime.h>
#include <hip/hip_bf16.h>

// Shapes fixed by the reference: B=8, C=32, H=64, W=512, NCHW.
#define CH   32
#define WD   512
#define NH   64
#define CHST (NH * WD)      // channel stride in floats
#define BST  (CH * CHST)    // batch stride in floats
#define NST  36             // N LDS row stride in f32 (144B: 16B-aligned)

typedef short bf16x8 __attribute__((ext_vector_type(8)));
typedef float f32x16 __attribute__((ext_vector_type(16)));
typedef float f32x8  __attribute__((ext_vector_type(8)));

__device__ __forceinline__ unsigned short f2bf(float f) {
  union { __hip_bfloat16 h; unsigned short u; } cv;
  cv.h = __float2bfloat16(f);
  return cv.u;
}
__device__ __forceinline__ float bf2f(unsigned short u) {
  return __uint_as_float(((unsigned int)u) << 16);
}
__device__ __forceinline__ unsigned int pk2(float lo_, float hi_) {
  return ((unsigned int)f2bf(hi_) << 16) | (unsigned int)f2bf(lo_);
}
// v_permlane32_swap_b32 a,b — half-swap. ONLY safe when a,b are distinct SSA
// values (regalloc may coalesce identical values into one VGPR — R7's bug).
__device__ __forceinline__ void swap32(unsigned int& a, unsigned int& b) {
  asm volatile("v_permlane32_swap_b32 %0, %1" : "+v"(a), "+v"(b));
}
union W4 { unsigned int u[4]; bf16x8 v; };

// D-layout f32x16 -> two B-fragments (bf16) of the same matrix (verified R3-R13).
__device__ __forceinline__ void d2frag(const f32x16& d, W4& f0, W4& f1) {
  f0.u[0] = pk2(d[0], d[1]);   f0.u[1] = pk2(d[2],  d[3]);
  f0.u[2] = pk2(d[4], d[5]);   f0.u[3] = pk2(d[6],  d[7]);
  swap32(f0.u[0], f0.u[2]);    swap32(f0.u[1], f0.u[3]);
  f1.u[0] = pk2(d[8], d[9]);   f1.u[1] = pk2(d[10], d[11]);
  f1.u[2] = pk2(d[12], d[13]); f1.u[3] = pk2(d[14], d[15]);
  swap32(f1.u[0], f1.u[2]);    swap32(f1.u[1], f1.u[3]);
}
// cross-half sum via shuffle — immune to the asm coalescing hazard (R8-verified).
__device__ __forceinline__ float halfsum(float v) {
  return v + __shfl_xor(v, 32, 64);
}

// One block per (b,h) (grid 512, 512 thr) — R10, the measured best (28.9 us;
// reproduced 29.8 us R13). Final form.
// Lessons measured & locked: (R9) never duplicate k/v reads — L3 won't absorb
// them (+33MB FETCH); (R8/R11) two independent blocks/CU beat any bigger or
// software-pipelined single block; (R12) cross-block atomic reduction costs
// ~94MB of sync traffic; (R14) producer/consumer specialization idles half the
// machine during the producer phase. q loads issue right after k/v so all
// 192KB of reads stream from t=0; only the out-store tail remains exposed.
//   N = K*V^T; M = Wk*N*Wv^T + (Wk sK) bv^T + bk (Wv sV + 512 bv)^T
//   G = Wq^T*M (+I residual), g = bq*M;  out = G^T q + g.
// MFMA 32x32x16 layouts (verified): A: a[s][j]=A[lo][16s+8hi+j];
// B: b[s][j]=B[16s+8hi+j][lo]; D: d[r]=D[(r&3)+8(r>>2)+4hi][lo].
__global__ __launch_bounds__(512, 4)
void fused_mha(const float* __restrict__ qg, const float* __restrict__ kg,
               const float* __restrict__ vg,
               const float* __restrict__ wqg, const float* __restrict__ bqg,
               const float* __restrict__ wkg, const float* __restrict__ bkg,
               const float* __restrict__ wvg, const float* __restrict__ bvg,
               float* __restrict__ outg)
{
  __shared__ float np[8][CH][NST];   // per-wave partial N; np[0] = reduced N
  __shared__ float sp[8][2][CH];     // per-wave partial sK,sV; sp[0] = reduced

  const int t = threadIdx.x, lane = t & 63, wid = t >> 6;   // wid 0..7
  const int lo = lane & 31, hi = lane >> 5;
  const int bh = blockIdx.x;
  const size_t base = (size_t)(bh >> 6) * BST + (size_t)(bh & 63) * WD;

  int rowr[16];
  #pragma unroll
  for (int r = 0; r < 16; ++r) rowr[r] = (r & 3) + 8 * (r >> 2) + 4 * hi;

  // ---- Issue ALL global reads up front: k/v first (phase-1 deps), then q ----------
  const float* krow = kg + base + (size_t)lo * CHST + 64 * wid + 8 * hi;
  const float* vrow = vg + base + (size_t)lo * CHST + 64 * wid + 8 * hi;
  f32x8 kf[4], vf[4];
  #pragma unroll
  for (int kk = 0; kk < 4; ++kk) {
    kf[kk] = *(const f32x8*)(krow + 16 * kk);
    vf[kk] = *(const f32x8*)(vrow + 16 * kk);
  }
  float qpf[32];
  #pragma unroll
  for (int it = 0; it < 2; ++it)
    #pragma unroll
    for (int s = 0; s < 2; ++s)
      #pragma unroll
      for (int j = 0; j < 8; ++j)
        qpf[16 * it + 8 * s + j] =
            qg[base + (size_t)(16 * s + 8 * hi + j) * CHST + 64 * wid + 32 * it + lo];

  // Wk/Wv A-fragments (bf16) — wv also serves as B-frag of Wv^T in phase 3.
  bf16x8 wkA[2], wvA[2];
  {
    const float* wk_r = wkg + lo * CH + 8 * hi;
    const float* wv_r = wvg + lo * CH + 8 * hi;
    #pragma unroll
    for (int s = 0; s < 2; ++s)
      #pragma unroll
      for (int j = 0; j < 8; ++j) {
        wkA[s][j] = (short)f2bf(wk_r[16 * s + j]);
        wvA[s][j] = (short)f2bf(wv_r[16 * s + j]);
      }
  }

  // ---- Phase 1: N partial + sK/sV partial (waits only on kf/vf) -------------------
  f32x16 nacc;
  #pragma unroll
  for (int r = 0; r < 16; ++r) nacc[r] = 0.f;
  float psK = 0.f, psV = 0.f;
  #pragma unroll
  for (int kk = 0; kk < 4; ++kk) {
    W4 kb, vb;
    #pragma unroll
    for (int i = 0; i < 4; ++i) {
      kb.u[i] = pk2(kf[kk][2 * i], kf[kk][2 * i + 1]);
      vb.u[i] = pk2(vf[kk][2 * i], vf[kk][2 * i + 1]);
    }
    nacc = __builtin_amdgcn_mfma_f32_32x32x16_bf16(kb.v, vb.v, nacc, 0, 0, 0);
    #pragma unroll
    for (int j = 0; j < 8; ++j) { psK += kf[kk][j]; psV += vf[kk][j]; }
  }
  #pragma unroll
  for (int r = 0; r < 16; ++r) np[wid][rowr[r]][lo] = nacc[r];
  {
    const float sk = halfsum(psK), sv = halfsum(psV);
    if (hi == 0) { sp[wid][0][lo] = sk; sp[wid][1][lo] = sv; }
  }

  __syncthreads();

  // ---- Reduce 8 partials (two entries per thread) ----------------------------------
  {
    #pragma unroll
    for (int p = 0; p < 2; ++p) {
      const int e = t + 512 * p, o = e >> 5, c = e & 31;
      float s = 0.f;
      #pragma unroll
      for (int w = 0; w < 8; ++w) s += np[w][o][c];
      np[0][o][c] = s;
    }
    if (t < 64) {
      const int j = t >> 5, oo = t & 31;
      float s2 = 0.f;
      #pragma unroll
      for (int w = 0; w < 8; ++w) s2 += sp[w][j][oo];
      sp[0][j][oo] = s2;
    }
  }
  __syncthreads();

  // Wq A-fragment (A of Wq^T), biases
  bf16x8 wqA[2];
  {
    #pragma unroll
    for (int s = 0; s < 2; ++s)
      #pragma unroll
      for (int j = 0; j < 8; ++j)
        wqA[s][j] = (short)f2bf(wqg[(16 * s + 8 * hi + j) * CH + lo]);
  }
  float bkr[16], bqr[16];
  #pragma unroll
  for (int r = 0; r < 16; ++r) { bkr[r] = bkg[rowr[r]]; bqr[r] = bqg[rowr[r]]; }
  const float bvlo = bvg[lo];

  // ---- Phase 3 (per-wave redundant, all in registers) ------------------------------
  // N A-fragments, hi/lo split (error-free N path).
  W4 NAh[2], NAl[2];
  #pragma unroll
  for (int s = 0; s < 2; ++s) {
    f32x8 nf = *(const f32x8*)&np[0][lo][16 * s + 8 * hi];
    #pragma unroll
    for (int i = 0; i < 4; ++i) {
      const float x = nf[2 * i], y = nf[2 * i + 1];
      const unsigned short hx = f2bf(x), hy = f2bf(y);
      NAh[s].u[i] = ((unsigned int)hy << 16) | hx;
      NAl[s].u[i] = pk2(x - bf2f(hx), y - bf2f(hy));
    }
  }
  // P = N * Wv^T
  f32x16 pacc;
  #pragma unroll
  for (int r = 0; r < 16; ++r) pacc[r] = 0.f;
  pacc = __builtin_amdgcn_mfma_f32_32x32x16_bf16(NAh[0].v, wvA[0], pacc, 0, 0, 0);
  pacc = __builtin_amdgcn_mfma_f32_32x32x16_bf16(NAh[1].v, wvA[1], pacc, 0, 0, 0);
  pacc = __builtin_amdgcn_mfma_f32_32x32x16_bf16(NAl[0].v, wvA[0], pacc, 0, 0, 0);
  pacc = __builtin_amdgcn_mfma_f32_32x32x16_bf16(NAl[1].v, wvA[1], pacc, 0, 0, 0);
  // P' = P + sK * bv^T
  f32x16 pp;
  #pragma unroll
  for (int r = 0; r < 16; ++r) pp[r] = pacc[r] + sp[0][0][rowr[r]] * bvlo;
  // u[lo] = (Wv sV)[lo] + 512*bv[lo]
  float uprt = 0.f;
  #pragma unroll
  for (int s = 0; s < 2; ++s)
    #pragma unroll
    for (int j = 0; j < 8; ++j)
      uprt += bf2f((unsigned short)wvA[s][j]) * sp[0][1][16 * s + 8 * hi + j];
  const float uful = halfsum(uprt) + 512.f * bvlo;
  // M = Wk * P' (hi/lo) + bk * u^T     (D-layout)
  f32x16 pres;
  #pragma unroll
  for (int r = 0; r < 16; ++r) pres[r] = pp[r] - bf2f(f2bf(pp[r]));
  W4 pb0h, pb1h, pb0l, pb1l;
  d2frag(pp, pb0h, pb1h);
  d2frag(pres, pb0l, pb1l);
  f32x16 mac;
  #pragma unroll
  for (int r = 0; r < 16; ++r) mac[r] = bkr[r] * uful;
  mac = __builtin_amdgcn_mfma_f32_32x32x16_bf16(wkA[0], pb0h.v, mac, 0, 0, 0);
  mac = __builtin_amdgcn_mfma_f32_32x32x16_bf16(wkA[1], pb1h.v, mac, 0, 0, 0);
  mac = __builtin_amdgcn_mfma_f32_32x32x16_bf16(wkA[0], pb0l.v, mac, 0, 0, 0);
  mac = __builtin_amdgcn_mfma_f32_32x32x16_bf16(wkA[1], pb1l.v, mac, 0, 0, 0);
  // G = Wq^T * M (+I), g = bq * M
  W4 mb0, mb1;
  d2frag(mac, mb0, mb1);
  f32x16 gacc;
  #pragma unroll
  for (int r = 0; r < 16; ++r) gacc[r] = 0.f;
  gacc = __builtin_amdgcn_mfma_f32_32x32x16_bf16(wqA[0], mb0.v, gacc, 0, 0, 0);
  gacc = __builtin_amdgcn_mfma_f32_32x32x16_bf16(wqA[1], mb1.v, gacc, 0, 0, 0);
  #pragma unroll
  for (int r = 0; r < 16; ++r)
    if (rowr[r] == lo) gacc[r] += 1.f;            // residual: +I on G's diagonal
  float part = 0.f;
  #pragma unroll
  for (int r = 0; r < 16; ++r) part = fmaf(bqr[r], mac[r], part);
  const float gv = halfsum(part);                  // g[lo]
  // G (D-layout) -> fragments usable as A of G^T
  W4 ga0, ga1;
  d2frag(gacc, ga0, ga1);
  float gsh[16];
  #pragma unroll
  for (int r = 0; r < 16; ++r) gsh[r] = __shfl(gv, rowr[r], 64);

  // ---- Phase 4: out = G^T * q + g (this wave's 64 px, q already resident) ----------
  #pragma unroll
  for (int it = 0; it < 2; ++it) {
    const int x0 = 64 * wid + 32 * it;
    bf16x8 qb[2];
    #pragma unroll
    for (int s = 0; s < 2; ++s)
      #pragma unroll
      for (int j = 0; j < 8; ++j)
        qb[s][j] = (short)f2bf(qpf[16 * it + 8 * s + j]);
    f32x16 acc;
    #pragma unroll
    for (int r = 0; r < 16; ++r) acc[r] = gsh[r];
    acc = __builtin_amdgcn_mfma_f32_32x32x16_bf16(ga0.v, qb[0], acc, 0, 0, 0);
    acc = __builtin_amdgcn_mfma_f32_32x32x16_bf16(ga1.v, qb[1], acc, 0, 0, 0);
    #pragma unroll
    for (int r = 0; r < 16; ++r)
      outg[base + (size_t)rowr[r] * CHST + x0 + lo] = acc[r];
  }
}

extern "C" void kernel_launch(void* const* d_in, const int* in_sizes, int n_in,
                              void* d_out, int out_size, void* d_ws, size_t ws_size,
                              hipStream_t stream) {
  const float* q  = (const float*)d_in[0];
  const float* k  = (const float*)d_in[1];
  const float* v  = (const float*)d_in[2];
  const float* wq = (const float*)d_in[3];
  const float* bq = (const float*)d_in[4];
  const float* wk = (const float*)d_in[5];
  const float* bk = (const float*)d_in[6];
  const float* wv = (const float*)d_in[7];
  const float* bv = (const float*)d_in[8];
  float* out = (float*)d_out;

  (void)in_sizes; (void)n_in; (void)out_size; (void)d_ws; (void)ws_size;

  fused_mha<<<dim3(8 * 64), dim3(512), 0, stream>>>(q, k, v, wq, bq, wk, bk, wv, bv, out);
}